// Round 4
// baseline (566.698 us; speedup 1.0000x reference)
//
#include <hip/hip_runtime.h>
#include <math.h>

// Cyborg stack machine: B=256, S=128, V=512, H=30, N_STACKS=2, R=2, DEPTH=4
// All stack/peek/output vectors live in span{ones, init_vec, syms0..29} (32-dim).
// kA (R6): split-f16 MFMA GEMM (x=xh+xl, w=wh+wl; 3 MFMAs; fp32-grade precision).
// kC (R8 redesign, R9 compile fix): DS-latency/LDS-pipe-bound scan -> VALU cross-lane.
//   - pk vector gathered via v_readlane (SGPR broadcast): dots+Gram use SGPR
//     operands, no pkL LDS buffer at all.
//   - both stack norms per-lane (M row is k-independent) with DPP rotation
//     butterfly (template ctrl) + 1 ds_swizzle xor16; rsqrt instead of sqrt+rcp.
//   - ONE barrier/step (double-buffered nndL); pkOther carried in register.

#define SS 128
#define VV 512
#define NROWS 208      // 8 pop + 8 pushop + 128 pushfn + 64 calc
#define ZOFF 1e-6f

// ws layout (float offsets)
#define OFF_I0   0                          // interp0: 32768*208
#define OFF_OC   (32768*208)                // out coords: 32768*32
#define OFF_GI   (OFF_OC + 32768*32)        // G[2][32][208]  (stack, basis, row)
#define OFF_M    (OFF_GI + 2*32*208)        // Gram 32*32
#define OFF_A    (OFF_M + 1024)             // A coef 208*3
#define OFF_Bc   (OFF_A + 624)              // B coef 208*3
#define OFF_W0   (OFF_Bc + 624)             // Wh/Wl f16: 2 x [208][512] halves

typedef _Float16 half8 __attribute__((ext_vector_type(8)));
typedef float f32x4 __attribute__((ext_vector_type(4)));

__device__ __forceinline__ float rlane(float v, int lane) {
    return __int_as_float(__builtin_amdgcn_readlane(__float_as_int(v), lane));
}
template <int CTRL>
__device__ __forceinline__ float dpp_add(float x) {
    int y = __builtin_amdgcn_update_dpp(0, __float_as_int(x), CTRL, 0xF, 0xF, true);
    return x + __int_as_float(y);
}
// full 16-lane row sum, result in all lanes of the row
__device__ __forceinline__ float sum16(float x) {
    x = dpp_add<0xB1>(x);    // quad_perm [1,0,3,2]  (xor 1)
    x = dpp_add<0x4E>(x);    // quad_perm [2,3,0,1]  (xor 2)
    x = dpp_add<0x124>(x);   // row_ror:4
    x = dpp_add<0x128>(x);   // row_ror:8
    return x;
}
__device__ __forceinline__ float swz16(float x) {   // lane ^ 16 within 32-group
    return __int_as_float(__builtin_amdgcn_ds_swizzle(__float_as_int(x), 0x401F));
}

__device__ __forceinline__ const float* w_row(int r, const float* pw, const float* pow_,
                                              const float* pfw, const float* cw) {
    if (r < 8)   return pw   + r * 1536;
    if (r < 16)  return pow_ + (r - 8) * 1536;
    if (r < 144) return pfw  + (r - 16) * 1536;
    return cw + (r - 144) * 1536;
}
__device__ __forceinline__ const float* nw_row(int r, const float* pn, const float* pon,
                                               const float* pfn, const float* cn) {
    if (r < 8)   return pn   + r * 3;
    if (r < 16)  return pon  + (r - 8) * 3;
    if (r < 144) return pfn  + (r - 16) * 3;
    return cn + (r - 144) * 3;
}

// ---------------- kernel B: precompute tables ----------------
__global__ void kB(const float* __restrict__ syms, const float* __restrict__ siv,
                   const float* __restrict__ pw, const float* __restrict__ pn,
                   const float* __restrict__ pow_, const float* __restrict__ pon,
                   const float* __restrict__ pfw, const float* __restrict__ pfn,
                   const float* __restrict__ cw, const float* __restrict__ cn,
                   float* __restrict__ ws) {
    int blk = blockIdx.x, tid = threadIdx.x;
    if (blk < 64) {
        // G[jj][e][c] = basis_e . w_row(c)[(jj+1)*512 ..)
        int jj = blk >> 5, e = blk & 31;
        __shared__ float bas[512];
        for (int i = tid; i < 512; i += 256)
            bas[i] = (e == 0) ? 1.0f : ((e == 1) ? siv[i] : syms[(e - 2) * 512 + i]);
        __syncthreads();
        if (tid < NROWS) {
            int c = tid;
            const float4* w4 = (const float4*)(w_row(c, pw, pow_, pfw, cw) + (jj + 1) * 512);
            const float4* b4 = (const float4*)bas;
            float s = 0.f;
            for (int q = 0; q < 128; ++q) {
                float4 a = b4[q], b = w4[q];
                s += a.x * b.x + a.y * b.y + a.z * b.z + a.w * b.w;
            }
            ws[OFF_GI + (jj * 32 + e) * 208 + c] = s;
        }
    } else if (blk == 64) {
        // Gram M[m][mm]
        __shared__ float basw[32 * 512];
        for (int i = tid; i < 32 * 512; i += 256) {
            int m = i >> 9, v = i & 511;
            basw[i] = (m == 0) ? 1.0f : ((m == 1) ? siv[v] : syms[(m - 2) * 512 + v]);
        }
        __syncthreads();
        for (int p = tid; p < 1024; p += 256) {
            int m = p >> 5, mm = p & 31;
            const float4* a4 = (const float4*)(basw + m * 512);
            const float4* b4 = (const float4*)(basw + mm * 512);
            float s = 0.f;
            for (int q = 0; q < 128; ++q) {
                float4 a = a4[q], b = b4[q];
                s += a.x * b.x + a.y * b.y + a.z * b.z + a.w * b.w;
            }
            ws[OFF_M + p] = s;
        }
    } else if (blk == 65) {
        // folded NAND coefs: A=(2*sig-1)/||w||, B=1-sig   for (r, j)
        for (int idx = tid; idx < 624; idx += 256) {
            int r = idx / 3, j = idx % 3;
            const float4* w4 = (const float4*)(w_row(r, pw, pow_, pfw, cw) + j * 512);
            float s = 0.f;
            for (int q = 0; q < 128; ++q) {
                float4 b = w4[q];
                s += b.x * b.x + b.y * b.y + b.z * b.z + b.w * b.w;
            }
            float nrm = fmaxf(sqrtf(s), 1e-8f);
            float nwv = nw_row(r, pn, pon, pfn, cn)[j];
            float sig = 1.f / (1.f + expf(-nwv));
            ws[OFF_A + idx]  = (2.f * sig - 1.f) / nrm;
            ws[OFF_Bc + idx] = 1.f - sig;
        }
    } else {
        // gather w j=0 slice as split-f16 hi/lo: Wh/Wl [208][512] halves — 16 blocks
        int part = blk - 66;
        _Float16* whp = (_Float16*)(ws + OFF_W0);
        _Float16* wlp = whp + 208 * 512;
        for (int i = tid; i < 6656; i += 256) {
            int flat = part * 6656 + i;
            int c = flat >> 9, v = flat & 511;
            float wv = w_row(c, pw, pow_, pfw, cw)[v];
            _Float16 h = (_Float16)wv;
            whp[flat] = h;
            wlp[flat] = (_Float16)(wv - (float)h);
        }
    }
}

// ---------------- kernel A: interp0 via split-f16 MFMA GEMM ----------------
__global__ __launch_bounds__(256) void kA(const float* __restrict__ x, float* __restrict__ ws) {
    __shared__ half8 AH[2][256];   // [buf][mfrag*64 + fraglane]
    __shared__ half8 AL[2][256];
    __shared__ float red[256];
    __shared__ float invx[64];
    const int tid = threadIdx.x;
    const int wid = tid >> 6, l = tid & 63;
    const size_t bt0 = (size_t)blockIdx.x * 64;

    const int sr = tid >> 2, ss = tid & 3;
    const float* xp = x + (bt0 + sr) * 512 + ss * 8;
    const int wpos = (sr >> 4) * 64 + (sr & 15) + (ss << 4);   // frag slot

    const _Float16* whp = (const _Float16*)(ws + OFF_W0);
    const _Float16* wlp = whp + 208 * 512;

    const int t0 = (wid == 0) ? 0 : (1 + 3 * wid);   // 0,4,7,10
    const int nt = (wid == 0) ? 4 : 3;

    f32x4 acc[4][4];
#pragma unroll
    for (int m = 0; m < 4; ++m)
#pragma unroll
        for (int tt = 0; tt < 4; ++tt)
            acc[m][tt] = (f32x4){0.f, 0.f, 0.f, 0.f};

    float sumsq = 0.f;
    auto stage = [&](int kt, int buf) {
        float v[8];
        *(float4*)v       = *(const float4*)(xp + kt * 32);
        *(float4*)(v + 4) = *(const float4*)(xp + kt * 32 + 4);
        half8 hh, hl;
#pragma unroll
        for (int j = 0; j < 8; ++j) {
            sumsq += v[j] * v[j];
            _Float16 h = (_Float16)v[j];
            hh[j] = h;
            hl[j] = (_Float16)(v[j] - (float)h);
        }
        AH[buf][wpos] = hh;
        AL[buf][wpos] = hl;
    };

    stage(0, 0);
    __syncthreads();

    for (int kt = 0; kt < 16; ++kt) {
        const int buf = kt & 1;
        if (kt < 15) stage(kt + 1, buf ^ 1);

        half8 ahm[4], alm[4];
#pragma unroll
        for (int m = 0; m < 4; ++m) {
            ahm[m] = AH[buf][m * 64 + l];
            alm[m] = AL[buf][m * 64 + l];
        }
        const int kof = kt * 32 + (l >> 4) * 8;
#pragma unroll
        for (int tt = 0; tt < 4; ++tt) {
            if (tt < nt) {
                const int c = (t0 + tt) * 16 + (l & 15);
                half8 bh = *(const half8*)(whp + c * 512 + kof);
                half8 bl = *(const half8*)(wlp + c * 512 + kof);
#pragma unroll
                for (int m = 0; m < 4; ++m) {
                    acc[m][tt] = __builtin_amdgcn_mfma_f32_16x16x32_f16(ahm[m], bh, acc[m][tt], 0, 0, 0);
                    acc[m][tt] = __builtin_amdgcn_mfma_f32_16x16x32_f16(ahm[m], bl, acc[m][tt], 0, 0, 0);
                    acc[m][tt] = __builtin_amdgcn_mfma_f32_16x16x32_f16(alm[m], bh, acc[m][tt], 0, 0, 0);
                }
            }
        }
        __syncthreads();
    }

    red[tid] = sumsq;
    __syncthreads();
    if (tid < 64) {
        float s = red[tid * 4] + red[tid * 4 + 1] + red[tid * 4 + 2] + red[tid * 4 + 3];
        invx[tid] = 1.f / fmaxf(sqrtf(s), 1e-8f);
    }
    __syncthreads();

    // epilogue: interp0 = A0*|dot|*invx + B0.  D frag: col=lane&15, row=(lane>>4)*4+reg
#pragma unroll
    for (int tt = 0; tt < 4; ++tt) {
        if (tt < nt) {
            const int c = (t0 + tt) * 16 + (l & 15);
            const float A0 = ws[OFF_A + c * 3];
            const float B0 = ws[OFF_Bc + c * 3];
#pragma unroll
            for (int m = 0; m < 4; ++m) {
                const int rbase = m * 16 + (l >> 4) * 4;
#pragma unroll
                for (int j = 0; j < 4; ++j) {
                    const float ix = invx[rbase + j];
                    ws[OFF_I0 + (bt0 + rbase + j) * 208 + c] = A0 * fabsf(acc[m][tt][j]) * ix + B0;
                }
            }
        }
    }
}

// ---------------- kernel C: serial scan, 1 barrier/step, VALU cross-lane ----------------
// tid 0..143: phase-1 row tid (G1[64] regs). wave3: calc row 144+l (G2[64] regs).
// All waves: replicated stack state + Mrow[32] (M row is k-independent).
// Per step: gates(nndL[t&1]) -> update -> pkp -> readlane-gather dots+Gram ->
// DPP+swz16 norms -> nnd -> nndL[(t+1)&1] / oc store -> ONE barrier.
__global__ __attribute__((amdgpu_flat_work_group_size(256, 256), amdgpu_waves_per_eu(1, 1)))
void kC(float* __restrict__ ws, const float* __restrict__ sharp) {
    __shared__ float nndL[2][144];
    const int b = blockIdx.x, tid = threadIdx.x;
    const int wid = tid >> 6, l = tid & 63;
    const int k = l >> 5, m = l & 31;
    const int isRow = (tid < 144);
    const int r2 = 144 + l;            // wave3's calc row

    const float* GI = ws + OFF_GI;
    float G1[64], G2[64], Mrow[32];
    float A1r = 0.f, A2r = 0.f, B1r = 0.f, B2r = 0.f;
    float A1d = 0.f, A2d = 0.f, B1d = 0.f, B2d = 0.f;
    if (isRow) {
#pragma unroll
        for (int i = 0; i < 32; ++i) {
            G1[i]      = GI[i * 208 + tid];
            G1[32 + i] = GI[(32 + i) * 208 + tid];
        }
        A1r = ws[OFF_A + tid * 3 + 1];  A2r = ws[OFF_A + tid * 3 + 2];
        B1r = ws[OFF_Bc + tid * 3 + 1]; B2r = ws[OFF_Bc + tid * 3 + 2];
    }
    if (wid == 3) {
#pragma unroll
        for (int i = 0; i < 32; ++i) {
            G2[i]      = GI[i * 208 + r2];
            G2[32 + i] = GI[(32 + i) * 208 + r2];
        }
        A1d = ws[OFF_A + r2 * 3 + 1];  A2d = ws[OFF_A + r2 * 3 + 2];
        B1d = ws[OFF_Bc + r2 * 3 + 1]; B2d = ws[OFF_Bc + r2 * 3 + 2];
    }
#pragma unroll
    for (int q = 0; q < 8; ++q) {
        float4 mr = *(const float4*)(ws + OFF_M + m * 32 + 4 * q);
        Mrow[4*q] = mr.x; Mrow[4*q+1] = mr.y; Mrow[4*q+2] = mr.z; Mrow[4*q+3] = mr.w;
    }
    const float sh = sharp[k];

    // replicated stack state
    float st[4], p[4];
#pragma unroll
    for (int d = 0; d < 4; ++d) {
        st[d] = (d == 1) ? ((m == 1) ? 1.f : 0.f) : ((m == 0) ? ZOFF : 0.f);
        p[d] = (d == 1) ? 1.f : 0.f;
    }
    float pk = st[0] * p[0] + st[1] * p[1] + st[2] * p[2] + st[3] * p[3];
    float pkOther = __shfl_xor(pk, 32);

    const float* i0base = ws + OFF_I0 + (size_t)b * SS * 208;
    float i0r  = isRow ? i0base[tid] : 0.f;        // i0(0)
    float i0d  = (wid == 3) ? i0base[r2] : 0.f;    // i0d(0)
    float i0rn = 0.f;

    // post-update work: gather pk vector by readlane, dots + both Gram norms,
    // nnd row values (rows -> nndW) / calc values + oc store (wave3).
    auto post = [&](float pkp, float pkpOth, float iv, float* nndW, bool doOc, int t) {
        float pk0v = k ? pkpOth : pkp;   // pk0[m] for this lane
        float pk1v = k ? pkp : pkpOth;   // pk1[m]
        float gq0[2] = {0.f, 0.f}, gq1[2] = {0.f, 0.f};
        float d1[2] = {0.f, 0.f}, d2[2] = {0.f, 0.f};
        if (wid == 3) {
#pragma unroll
            for (int mm = 0; mm < 32; ++mm) {
                float v0 = rlane(pkp, mm);
                float v1 = rlane(pkp, 32 + mm);
                gq0[mm & 1] += Mrow[mm] * v0;
                gq1[mm & 1] += Mrow[mm] * v1;
                d1[mm & 1]  += v0 * G2[mm];
                d2[mm & 1]  += v1 * G2[32 + mm];
            }
        } else {
#pragma unroll
            for (int mm = 0; mm < 32; ++mm) {
                float v0 = rlane(pkp, mm);
                float v1 = rlane(pkp, 32 + mm);
                gq0[mm & 1] += Mrow[mm] * v0;
                gq1[mm & 1] += Mrow[mm] * v1;
                d1[mm & 1]  += v0 * G1[mm];
                d2[mm & 1]  += v1 * G1[32 + mm];
            }
        }
        float pm0 = pk0v * (gq0[0] + gq0[1]);
        float pm1 = pk1v * (gq1[0] + gq1[1]);
        float q0 = sum16(pm0); q0 += swz16(q0);
        float q1 = sum16(pm1); q1 += swz16(q1);
        float iq0 = __frsqrt_rn(fmaxf(q0, 1e-16f));
        float iq1 = __frsqrt_rn(fmaxf(q1, 1e-16f));
        float dd1 = d1[0] + d1[1], dd2 = d2[0] + d2[1];
        if (isRow) {
            nndW[tid] = iv * (A1r * fabsf(dd1) * iq0 + B1r) * (A2r * fabsf(dd2) * iq1 + B2r);
        }
        if (wid == 3) {
            float nnd2 = i0d * (A1d * fabsf(dd1) * iq0 + B1d) * (A2d * fabsf(dd2) * iq1 + B2d);
            if (doOc) {
                float s60 = rlane(nnd2, 60), s61 = rlane(nnd2, 61);
                float s62 = rlane(nnd2, 62), s63 = rlane(nnd2, 63);
                int src = (m >= 2) ? (2 * m - 4) : 0;
                float cx = __shfl(nnd2, src);
                float cy = __shfl(nnd2, src + 1);
                if (m < 2) { cx = 0.f; cy = 0.f; }
                if (l < 32) {
                    float oc = cx + cy + (s60 + s61) * pkp + (s62 + s63) * pkpOth;
                    ws[OFF_OC + ((size_t)b * SS + t) * 32 + m] = oc;
                }
            }
        }
    };

    // ---- prologue: nnd(0) from pk(0), iq(0), i0(0) ----
    post(pk, pkOther, i0r, nndL[0], false, 0);
    if (isRow) i0rn = i0base[208 + tid];   // i0(1)
    __syncthreads();

    for (int t = 0; t < SS; ++t) {
        const float* nb = nndL[t & 1];
        // prefetch next-step i0 early (covers global latency under this step)
        float i0f = 0.f, i0df = 0.f;
        if (isRow) {
            int tn2 = (t < SS - 2) ? (t + 2) : (SS - 1);
            i0f = i0base[(size_t)tn2 * 208 + tid];
        }
        if (wid == 3) {
            int tn = (t < SS - 1) ? (t + 1) : (SS - 1);
            i0df = i0base[(size_t)tn * 208 + r2];
        }

        // ---- gates + push_val + state update (replicated in all waves) ----
        float4 gp4 = *(const float4*)(nb + 4 * k);
        float4 gq4 = *(const float4*)(nb + 8 + 4 * k);
        float prp0 = 1.f / (1.f + __expf((fmaxf(gp4.z, gp4.w) - fmaxf(gp4.x, gp4.y)) * sh));
        float prq0 = 1.f / (1.f + __expf((fmaxf(gq4.z, gq4.w) - fmaxf(gq4.x, gq4.y)) * sh));
        float prp1 = 1.f - prp0, prq1 = 1.f - prq0;
        float prx = 0.f, pry = 0.f;
        if (m >= 2) {
            float2 pr2 = *(const float2*)(nb + 16 + 64 * k + 2 * m - 4);
            prx = pr2.x; pry = pr2.y;
        }
        float4 t30 = *(const float4*)(nb + 16 + 64 * k + 60);
        float pk0m = k ? pkOther : pk;
        float pk1m = k ? pk : pkOther;
        float pvc = prx + pry + (t30.x + t30.y) * pk0m + (t30.z + t30.w) * pk1m;

        float zc = (m == 0) ? ZOFF : 0.f;
        float s1[4], p1[4];
#pragma unroll
        for (int d = 0; d < 4; ++d) {
            float ps = st[d] * (1.f - p[d]) + zc * p[d];
            s1[d] = ps * prp0 + st[d] * prp1;
            p1[d] = p[(d + 1) & 3] * prp0 + p[d] * prp1;
        }
#pragma unroll
        for (int d = 0; d < 4; ++d) {
            float pu = p1[(d + 3) & 3];
            float su = s1[d] * (1.f - pu) + pvc * pu;
            st[d] = su * prq0 + s1[d] * prq1;
            p[d] = pu * prq0 + p1[d] * prq1;
        }
        float pkp = st[0] * p[0] + st[1] * p[1] + st[2] * p[2] + st[3] * p[3];
        float pkpOth = __shfl_xor(pkp, 32);

        post(pkp, pkpOth, i0rn, nndL[(t + 1) & 1], true, t);

        __syncthreads();   // nndL(t+1) visible for next step
        pk = pkp;
        pkOther = pkpOth;
        i0rn = i0f;
        if (wid == 3) i0d = i0df;
    }
}

// ---------------- kernel D: expand coords -> 512-dim output (barrier-free) ----------------
__global__ __launch_bounds__(256) void kD(const float* __restrict__ ws, const float* __restrict__ syms,
                                          const float* __restrict__ siv, float* __restrict__ out) {
    int t = threadIdx.x;
    int rg = t >> 6;
    int vc = (t & 63) * 8;
    size_t r0 = (size_t)blockIdx.x * 16 + rg * 4;
    const float* oc = ws + OFF_OC;
    float acc[4][8];
    float4 sv0 = *(const float4*)(siv + vc);
    float4 sv1 = *(const float4*)(siv + vc + 4);
#pragma unroll
    for (int rr = 0; rr < 4; ++rr) {
        float c0 = oc[(r0 + rr) * 32 + 0];
        float c1 = oc[(r0 + rr) * 32 + 1];
        acc[rr][0] = c0 + c1 * sv0.x; acc[rr][1] = c0 + c1 * sv0.y;
        acc[rr][2] = c0 + c1 * sv0.z; acc[rr][3] = c0 + c1 * sv0.w;
        acc[rr][4] = c0 + c1 * sv1.x; acc[rr][5] = c0 + c1 * sv1.y;
        acc[rr][6] = c0 + c1 * sv1.z; acc[rr][7] = c0 + c1 * sv1.w;
    }
    for (int mm = 0; mm < 30; ++mm) {
        float4 b0 = *(const float4*)(syms + mm * 512 + vc);
        float4 b1 = *(const float4*)(syms + mm * 512 + vc + 4);
#pragma unroll
        for (int rr = 0; rr < 4; ++rr) {
            float c = oc[(r0 + rr) * 32 + 2 + mm];
            acc[rr][0] += c * b0.x; acc[rr][1] += c * b0.y;
            acc[rr][2] += c * b0.z; acc[rr][3] += c * b0.w;
            acc[rr][4] += c * b1.x; acc[rr][5] += c * b1.y;
            acc[rr][6] += c * b1.z; acc[rr][7] += c * b1.w;
        }
    }
#pragma unroll
    for (int rr = 0; rr < 4; ++rr) {
        float* o = out + (r0 + rr) * 512 + vc;
        *(float4*)o       = make_float4(acc[rr][0], acc[rr][1], acc[rr][2], acc[rr][3]);
        *(float4*)(o + 4) = make_float4(acc[rr][4], acc[rr][5], acc[rr][6], acc[rr][7]);
    }
}

extern "C" void kernel_launch(void* const* d_in, const int* in_sizes, int n_in,
                              void* d_out, int out_size, void* d_ws, size_t ws_size,
                              hipStream_t stream) {
    const float* x    = (const float*)d_in[0];
    const float* syms = (const float*)d_in[1];
    const float* siv  = (const float*)d_in[2];
    const float* shp  = (const float*)d_in[3];
    const float* pw   = (const float*)d_in[4];
    const float* pn   = (const float*)d_in[5];
    const float* pow_ = (const float*)d_in[6];
    const float* pon  = (const float*)d_in[7];
    const float* pfw  = (const float*)d_in[8];
    const float* pfn  = (const float*)d_in[9];
    const float* cw   = (const float*)d_in[10];
    const float* cn   = (const float*)d_in[11];
    float* ws  = (float*)d_ws;
    float* out = (float*)d_out;

    hipLaunchKernelGGL(kB, dim3(82),   dim3(256), 0, stream,
                       syms, siv, pw, pn, pow_, pon, pfw, pfn, cw, cn, ws);
    hipLaunchKernelGGL(kA, dim3(512),  dim3(256), 0, stream, x, ws);
    hipLaunchKernelGGL(kC, dim3(256),  dim3(256), 0, stream, ws, shp);
    hipLaunchKernelGGL(kD, dim3(2048), dim3(256), 0, stream, ws, syms, siv, out);
}

// Round 5
// 405.028 us; speedup vs baseline: 1.3992x; 1.3992x over previous
//
#include <hip/hip_runtime.h>
#include <math.h>

// Cyborg stack machine: B=256, S=128, V=512, H=30, N_STACKS=2, R=2, DEPTH=4
// All stack/peek/output vectors live in span{ones, init_vec, syms0..29} (32-dim).
// kA (R6): split-f16 MFMA GEMM (x=xh+xl, w=wh+wl; 3 MFMAs; fp32-grade precision).
// kC (R10): R7 skeleton (2 barriers/step, LDS pkL broadcast) with surgical fixes:
//   - ONE unified row table G[64] per thread (r = wid3 ? 144+l : tid) -> no G2,
//     register-neutral vs R7 (R8's G1+G2+Mrow duplication spilled to scratch).
//   - butterfly reduce -> 4 DPP adds (template ctrl) + 1 ds_swizzle xor16; rsqrt.
//   - gram + dots share ONE set of pkL loads (16 b128/wave instead of 24).

#define SS 128
#define VV 512
#define NROWS 208      // 8 pop + 8 pushop + 128 pushfn + 64 calc
#define ZOFF 1e-6f

// ws layout (float offsets)
#define OFF_I0   0                          // interp0: 32768*208
#define OFF_OC   (32768*208)                // out coords: 32768*32
#define OFF_GI   (OFF_OC + 32768*32)        // G[2][32][208]  (stack, basis, row)
#define OFF_M    (OFF_GI + 2*32*208)        // Gram 32*32
#define OFF_A    (OFF_M + 1024)             // A coef 208*3
#define OFF_Bc   (OFF_A + 624)              // B coef 208*3
#define OFF_W0   (OFF_Bc + 624)             // Wh/Wl f16: 2 x [208][512] halves

typedef _Float16 half8 __attribute__((ext_vector_type(8)));
typedef float f32x4 __attribute__((ext_vector_type(4)));

__device__ __forceinline__ float rlane(float v, int lane) {
    return __int_as_float(__builtin_amdgcn_readlane(__float_as_int(v), lane));
}
template <int CTRL>
__device__ __forceinline__ float dpp_add(float x) {
    int y = __builtin_amdgcn_update_dpp(0, __float_as_int(x), CTRL, 0xF, 0xF, true);
    return x + __int_as_float(y);
}
// full 16-lane row sum, result in all lanes of the row (pure VALU)
__device__ __forceinline__ float sum16(float x) {
    x = dpp_add<0xB1>(x);    // quad_perm [1,0,3,2]  (xor 1)
    x = dpp_add<0x4E>(x);    // quad_perm [2,3,0,1]  (xor 2)
    x = dpp_add<0x124>(x);   // row_ror:4
    x = dpp_add<0x128>(x);   // row_ror:8
    return x;
}
__device__ __forceinline__ float swz16(float x) {   // lane ^ 16 within 32-group
    return __int_as_float(__builtin_amdgcn_ds_swizzle(__float_as_int(x), 0x401F));
}

__device__ __forceinline__ const float* w_row(int r, const float* pw, const float* pow_,
                                              const float* pfw, const float* cw) {
    if (r < 8)   return pw   + r * 1536;
    if (r < 16)  return pow_ + (r - 8) * 1536;
    if (r < 144) return pfw  + (r - 16) * 1536;
    return cw + (r - 144) * 1536;
}
__device__ __forceinline__ const float* nw_row(int r, const float* pn, const float* pon,
                                               const float* pfn, const float* cn) {
    if (r < 8)   return pn   + r * 3;
    if (r < 16)  return pon  + (r - 8) * 3;
    if (r < 144) return pfn  + (r - 16) * 3;
    return cn + (r - 144) * 3;
}

// ---------------- kernel B: precompute tables ----------------
__global__ void kB(const float* __restrict__ syms, const float* __restrict__ siv,
                   const float* __restrict__ pw, const float* __restrict__ pn,
                   const float* __restrict__ pow_, const float* __restrict__ pon,
                   const float* __restrict__ pfw, const float* __restrict__ pfn,
                   const float* __restrict__ cw, const float* __restrict__ cn,
                   float* __restrict__ ws) {
    int blk = blockIdx.x, tid = threadIdx.x;
    if (blk < 64) {
        // G[jj][e][c] = basis_e . w_row(c)[(jj+1)*512 ..)
        int jj = blk >> 5, e = blk & 31;
        __shared__ float bas[512];
        for (int i = tid; i < 512; i += 256)
            bas[i] = (e == 0) ? 1.0f : ((e == 1) ? siv[i] : syms[(e - 2) * 512 + i]);
        __syncthreads();
        if (tid < NROWS) {
            int c = tid;
            const float4* w4 = (const float4*)(w_row(c, pw, pow_, pfw, cw) + (jj + 1) * 512);
            const float4* b4 = (const float4*)bas;
            float s = 0.f;
            for (int q = 0; q < 128; ++q) {
                float4 a = b4[q], b = w4[q];
                s += a.x * b.x + a.y * b.y + a.z * b.z + a.w * b.w;
            }
            ws[OFF_GI + (jj * 32 + e) * 208 + c] = s;
        }
    } else if (blk == 64) {
        // Gram M[m][mm]
        __shared__ float basw[32 * 512];
        for (int i = tid; i < 32 * 512; i += 256) {
            int m = i >> 9, v = i & 511;
            basw[i] = (m == 0) ? 1.0f : ((m == 1) ? siv[v] : syms[(m - 2) * 512 + v]);
        }
        __syncthreads();
        for (int p = tid; p < 1024; p += 256) {
            int m = p >> 5, mm = p & 31;
            const float4* a4 = (const float4*)(basw + m * 512);
            const float4* b4 = (const float4*)(basw + mm * 512);
            float s = 0.f;
            for (int q = 0; q < 128; ++q) {
                float4 a = a4[q], b = b4[q];
                s += a.x * b.x + a.y * b.y + a.z * b.z + a.w * b.w;
            }
            ws[OFF_M + p] = s;
        }
    } else if (blk == 65) {
        // folded NAND coefs: A=(2*sig-1)/||w||, B=1-sig   for (r, j)
        for (int idx = tid; idx < 624; idx += 256) {
            int r = idx / 3, j = idx % 3;
            const float4* w4 = (const float4*)(w_row(r, pw, pow_, pfw, cw) + j * 512);
            float s = 0.f;
            for (int q = 0; q < 128; ++q) {
                float4 b = w4[q];
                s += b.x * b.x + b.y * b.y + b.z * b.z + b.w * b.w;
            }
            float nrm = fmaxf(sqrtf(s), 1e-8f);
            float nwv = nw_row(r, pn, pon, pfn, cn)[j];
            float sig = 1.f / (1.f + expf(-nwv));
            ws[OFF_A + idx]  = (2.f * sig - 1.f) / nrm;
            ws[OFF_Bc + idx] = 1.f - sig;
        }
    } else {
        // gather w j=0 slice as split-f16 hi/lo: Wh/Wl [208][512] halves — 16 blocks
        int part = blk - 66;
        _Float16* whp = (_Float16*)(ws + OFF_W0);
        _Float16* wlp = whp + 208 * 512;
        for (int i = tid; i < 6656; i += 256) {
            int flat = part * 6656 + i;
            int c = flat >> 9, v = flat & 511;
            float wv = w_row(c, pw, pow_, pfw, cw)[v];
            _Float16 h = (_Float16)wv;
            whp[flat] = h;
            wlp[flat] = (_Float16)(wv - (float)h);
        }
    }
}

// ---------------- kernel A: interp0 via split-f16 MFMA GEMM ----------------
__global__ __launch_bounds__(256) void kA(const float* __restrict__ x, float* __restrict__ ws) {
    __shared__ half8 AH[2][256];   // [buf][mfrag*64 + fraglane]
    __shared__ half8 AL[2][256];
    __shared__ float red[256];
    __shared__ float invx[64];
    const int tid = threadIdx.x;
    const int wid = tid >> 6, l = tid & 63;
    const size_t bt0 = (size_t)blockIdx.x * 64;

    const int sr = tid >> 2, ss = tid & 3;
    const float* xp = x + (bt0 + sr) * 512 + ss * 8;
    const int wpos = (sr >> 4) * 64 + (sr & 15) + (ss << 4);   // frag slot

    const _Float16* whp = (const _Float16*)(ws + OFF_W0);
    const _Float16* wlp = whp + 208 * 512;

    const int t0 = (wid == 0) ? 0 : (1 + 3 * wid);   // 0,4,7,10
    const int nt = (wid == 0) ? 4 : 3;

    f32x4 acc[4][4];
#pragma unroll
    for (int m = 0; m < 4; ++m)
#pragma unroll
        for (int tt = 0; tt < 4; ++tt)
            acc[m][tt] = (f32x4){0.f, 0.f, 0.f, 0.f};

    float sumsq = 0.f;
    auto stage = [&](int kt, int buf) {
        float v[8];
        *(float4*)v       = *(const float4*)(xp + kt * 32);
        *(float4*)(v + 4) = *(const float4*)(xp + kt * 32 + 4);
        half8 hh, hl;
#pragma unroll
        for (int j = 0; j < 8; ++j) {
            sumsq += v[j] * v[j];
            _Float16 h = (_Float16)v[j];
            hh[j] = h;
            hl[j] = (_Float16)(v[j] - (float)h);
        }
        AH[buf][wpos] = hh;
        AL[buf][wpos] = hl;
    };

    stage(0, 0);
    __syncthreads();

    for (int kt = 0; kt < 16; ++kt) {
        const int buf = kt & 1;
        if (kt < 15) stage(kt + 1, buf ^ 1);

        half8 ahm[4], alm[4];
#pragma unroll
        for (int m = 0; m < 4; ++m) {
            ahm[m] = AH[buf][m * 64 + l];
            alm[m] = AL[buf][m * 64 + l];
        }
        const int kof = kt * 32 + (l >> 4) * 8;
#pragma unroll
        for (int tt = 0; tt < 4; ++tt) {
            if (tt < nt) {
                const int c = (t0 + tt) * 16 + (l & 15);
                half8 bh = *(const half8*)(whp + c * 512 + kof);
                half8 bl = *(const half8*)(wlp + c * 512 + kof);
#pragma unroll
                for (int m = 0; m < 4; ++m) {
                    acc[m][tt] = __builtin_amdgcn_mfma_f32_16x16x32_f16(ahm[m], bh, acc[m][tt], 0, 0, 0);
                    acc[m][tt] = __builtin_amdgcn_mfma_f32_16x16x32_f16(ahm[m], bl, acc[m][tt], 0, 0, 0);
                    acc[m][tt] = __builtin_amdgcn_mfma_f32_16x16x32_f16(alm[m], bh, acc[m][tt], 0, 0, 0);
                }
            }
        }
        __syncthreads();
    }

    red[tid] = sumsq;
    __syncthreads();
    if (tid < 64) {
        float s = red[tid * 4] + red[tid * 4 + 1] + red[tid * 4 + 2] + red[tid * 4 + 3];
        invx[tid] = 1.f / fmaxf(sqrtf(s), 1e-8f);
    }
    __syncthreads();

    // epilogue: interp0 = A0*|dot|*invx + B0.  D frag: col=lane&15, row=(lane>>4)*4+reg
#pragma unroll
    for (int tt = 0; tt < 4; ++tt) {
        if (tt < nt) {
            const int c = (t0 + tt) * 16 + (l & 15);
            const float A0 = ws[OFF_A + c * 3];
            const float B0 = ws[OFF_Bc + c * 3];
#pragma unroll
            for (int m = 0; m < 4; ++m) {
                const int rbase = m * 16 + (l >> 4) * 4;
#pragma unroll
                for (int j = 0; j < 4; ++j) {
                    const float ix = invx[rbase + j];
                    ws[OFF_I0 + (bt0 + rbase + j) * 208 + c] = A0 * fabsf(acc[m][tt][j]) * ix + B0;
                }
            }
        }
    }
}

// ---------------- kernel C: serial scan, 2 barriers/step, unified row, DPP reduce ----------------
// Every thread owns row r = (wid==3)? 144+l : tid  (tid 144..191 = valid junk).
// All waves: replicated stack state + Mr[8] (Gram row, k-independent).
// Per step: gates(nndL[t&1]) -> update -> pkp -> publish pkL -> B2 ->
//   CA: one pass over pkL (16 b128) feeding gram(gq0,gq1) + dots(d1,d2) ->
//   DPP sum16 + swz16 -> iq -> nv -> nndL[(t+1)&1] / oc -> B1.
__global__ __attribute__((amdgpu_flat_work_group_size(256, 256), amdgpu_waves_per_eu(1, 1)))
void kC(float* __restrict__ ws, const float* __restrict__ sharp) {
    __shared__ float pkL[64];
    __shared__ float nndL[2][144];
    const int b = blockIdx.x, tid = threadIdx.x;
    const int wid = tid >> 6, l = tid & 63;
    const int k = l >> 5, m = l & 31;
    const int isW3 = (wid == 3);
    const int isRow = (tid < 144);
    const int r = isW3 ? (144 + l) : tid;          // owned NAND row

    const float* GI = ws + OFF_GI;
    float G[64];
#pragma unroll
    for (int i = 0; i < 32; ++i) {
        G[i]      = GI[i * 208 + r];
        G[32 + i] = GI[(32 + i) * 208 + r];
    }
    const float A1 = ws[OFF_A + r * 3 + 1],  A2 = ws[OFF_A + r * 3 + 2];
    const float B1 = ws[OFF_Bc + r * 3 + 1], B2 = ws[OFF_Bc + r * 3 + 2];
    float4 Mr[8];
#pragma unroll
    for (int q = 0; q < 8; ++q) Mr[q] = *(const float4*)(ws + OFF_M + m * 32 + 4 * q);
    const float sh = sharp[k];

    // replicated stack state
    float st[4], p[4];
#pragma unroll
    for (int d = 0; d < 4; ++d) {
        st[d] = (d == 1) ? ((m == 1) ? 1.f : 0.f) : ((m == 0) ? ZOFF : 0.f);
        p[d] = (d == 1) ? 1.f : 0.f;
    }
    float pk = st[0] * p[0] + st[1] * p[1] + st[2] * p[2] + st[3] * p[3];
    float pkOther = __shfl_xor(pk, 32);

    const float* i0base = ws + OFF_I0 + (size_t)b * SS * 208;
    const int ioff = isW3 ? 0 : 1;                 // rows consume i0(t+1), w3 i0(t)
    float i0pro = i0base[r];                       // i0(0) for prologue
    float i0use = i0base[(size_t)ioff * 208 + r];  // rows: i0(1), w3: i0(0)

    // CA: pkp/pkpOth published in pkL; iv = this thread's i0 operand -> nnd value
    auto CA = [&](float pp, float po, float iv) -> float {
        float gq0[2] = {0.f, 0.f}, gq1[2] = {0.f, 0.f};
        float d1[2] = {0.f, 0.f}, d2[2] = {0.f, 0.f};
#pragma unroll
        for (int q = 0; q < 8; ++q) {
            float4 aq = *(const float4*)(pkL + 4 * q);
            float4 cq = *(const float4*)(pkL + 32 + 4 * q);
            float4 mq = Mr[q];
            gq0[q & 1] += mq.x * aq.x + mq.y * aq.y + mq.z * aq.z + mq.w * aq.w;
            gq1[q & 1] += mq.x * cq.x + mq.y * cq.y + mq.z * cq.z + mq.w * cq.w;
            d1[q & 1]  += aq.x * G[4*q]   + aq.y * G[4*q+1]   + aq.z * G[4*q+2]   + aq.w * G[4*q+3];
            d2[q & 1]  += cq.x * G[32+4*q] + cq.y * G[33+4*q] + cq.z * G[34+4*q] + cq.w * G[35+4*q];
        }
        // both quadratic forms per lane: own pk0/pk1 component times (M.pk)
        float pm0 = (k ? po : pp) * (gq0[0] + gq0[1]);
        float pm1 = (k ? pp : po) * (gq1[0] + gq1[1]);
        float q0 = sum16(pm0); q0 += swz16(q0);
        float q1 = sum16(pm1); q1 += swz16(q1);
        float iq0 = __frsqrt_rn(fmaxf(q0, 1e-16f));
        float iq1 = __frsqrt_rn(fmaxf(q1, 1e-16f));
        float dd1 = d1[0] + d1[1], dd2 = d2[0] + d2[1];
        return iv * (A1 * fabsf(dd1) * iq0 + B1) * (A2 * fabsf(dd2) * iq1 + B2);
    };

    // ---- prologue: publish pk(0), nnd(0) -> nndL[0] ----
    if (wid == 0) pkL[l] = pk;
    __syncthreads();
    {
        float nv0 = CA(pk, pkOther, i0pro);
        if (isRow) nndL[0][tid] = nv0;
    }
    __syncthreads();

    for (int t = 0; t < SS; ++t) {
        // early prefetch of next i0 (global latency hides under this step)
        int nidx = t + 1 + ioff; if (nidx > SS - 1) nidx = SS - 1;
        float i0nxt = i0base[(size_t)nidx * 208 + r];

        const float* nb = nndL[t & 1];
        // ---- gates + push_val + state update (replicated in all waves) ----
        float4 gp4 = *(const float4*)(nb + 4 * k);
        float4 gq4 = *(const float4*)(nb + 8 + 4 * k);
        float prp0 = 1.f / (1.f + __expf((fmaxf(gp4.z, gp4.w) - fmaxf(gp4.x, gp4.y)) * sh));
        float prq0 = 1.f / (1.f + __expf((fmaxf(gq4.z, gq4.w) - fmaxf(gq4.x, gq4.y)) * sh));
        float prp1 = 1.f - prp0, prq1 = 1.f - prq0;
        float prx = 0.f, pry = 0.f;
        if (m >= 2) {
            float2 pr2 = *(const float2*)(nb + 16 + 64 * k + 2 * m - 4);
            prx = pr2.x; pry = pr2.y;
        }
        float4 t30 = *(const float4*)(nb + 16 + 64 * k + 60);
        float pk0m = k ? pkOther : pk;
        float pk1m = k ? pk : pkOther;
        float pvc = prx + pry + (t30.x + t30.y) * pk0m + (t30.z + t30.w) * pk1m;

        float zc = (m == 0) ? ZOFF : 0.f;
        float s1[4], p1[4];
#pragma unroll
        for (int d = 0; d < 4; ++d) {
            float ps = st[d] * (1.f - p[d]) + zc * p[d];
            s1[d] = ps * prp0 + st[d] * prp1;
            p1[d] = p[(d + 1) & 3] * prp0 + p[d] * prp1;
        }
#pragma unroll
        for (int d = 0; d < 4; ++d) {
            float pu = p1[(d + 3) & 3];
            float su = s1[d] * (1.f - pu) + pvc * pu;
            st[d] = su * prq0 + s1[d] * prq1;
            p[d] = pu * prq0 + p1[d] * prq1;
        }
        float pkp = st[0] * p[0] + st[1] * p[1] + st[2] * p[2] + st[3] * p[3];
        float pkpOth = __shfl_xor(pkp, 32);
        if (wid == 0) pkL[l] = pkp;
        __syncthreads();   // B2: pkL' visible

        // ---- region CA: fused gram + dots + nnd ----
        float nv = CA(pkp, pkpOth, i0use);
        if (isRow) nndL[(t + 1) & 1][tid] = nv;
        if (isW3) {
            // out coords via lane ops over per-lane nnd2 (calc row 144+lane)
            float s60 = rlane(nv, 60), s61 = rlane(nv, 61);
            float s62 = rlane(nv, 62), s63 = rlane(nv, 63);
            int src = (m >= 2) ? (2 * m - 4) : 0;
            float cx = __shfl(nv, src);
            float cy = __shfl(nv, src + 1);
            if (m < 2) { cx = 0.f; cy = 0.f; }
            if (l < 32) {
                float oc = cx + cy + (s60 + s61) * pkp + (s62 + s63) * pkpOth;
                ws[OFF_OC + ((size_t)b * SS + t) * 32 + m] = oc;
            }
        }
        __syncthreads();   // B1: nndL(t+1) visible
        pk = pkp;
        pkOther = pkpOth;
        i0use = i0nxt;
    }
}

// ---------------- kernel D: expand coords -> 512-dim output (barrier-free) ----------------
__global__ __launch_bounds__(256) void kD(const float* __restrict__ ws, const float* __restrict__ syms,
                                          const float* __restrict__ siv, float* __restrict__ out) {
    int t = threadIdx.x;
    int rg = t >> 6;
    int vc = (t & 63) * 8;
    size_t r0 = (size_t)blockIdx.x * 16 + rg * 4;
    const float* oc = ws + OFF_OC;
    float acc[4][8];
    float4 sv0 = *(const float4*)(siv + vc);
    float4 sv1 = *(const float4*)(siv + vc + 4);
#pragma unroll
    for (int rr = 0; rr < 4; ++rr) {
        float c0 = oc[(r0 + rr) * 32 + 0];
        float c1 = oc[(r0 + rr) * 32 + 1];
        acc[rr][0] = c0 + c1 * sv0.x; acc[rr][1] = c0 + c1 * sv0.y;
        acc[rr][2] = c0 + c1 * sv0.z; acc[rr][3] = c0 + c1 * sv0.w;
        acc[rr][4] = c0 + c1 * sv1.x; acc[rr][5] = c0 + c1 * sv1.y;
        acc[rr][6] = c0 + c1 * sv1.z; acc[rr][7] = c0 + c1 * sv1.w;
    }
    for (int mm = 0; mm < 30; ++mm) {
        float4 b0 = *(const float4*)(syms + mm * 512 + vc);
        float4 b1 = *(const float4*)(syms + mm * 512 + vc + 4);
#pragma unroll
        for (int rr = 0; rr < 4; ++rr) {
            float c = oc[(r0 + rr) * 32 + 2 + mm];
            acc[rr][0] += c * b0.x; acc[rr][1] += c * b0.y;
            acc[rr][2] += c * b0.z; acc[rr][3] += c * b0.w;
            acc[rr][4] += c * b1.x; acc[rr][5] += c * b1.y;
            acc[rr][6] += c * b1.z; acc[rr][7] += c * b1.w;
        }
    }
#pragma unroll
    for (int rr = 0; rr < 4; ++rr) {
        float* o = out + (r0 + rr) * 512 + vc;
        *(float4*)o       = make_float4(acc[rr][0], acc[rr][1], acc[rr][2], acc[rr][3]);
        *(float4*)(o + 4) = make_float4(acc[rr][4], acc[rr][5], acc[rr][6], acc[rr][7]);
    }
}

extern "C" void kernel_launch(void* const* d_in, const int* in_sizes, int n_in,
                              void* d_out, int out_size, void* d_ws, size_t ws_size,
                              hipStream_t stream) {
    const float* x    = (const float*)d_in[0];
    const float* syms = (const float*)d_in[1];
    const float* siv  = (const float*)d_in[2];
    const float* shp  = (const float*)d_in[3];
    const float* pw   = (const float*)d_in[4];
    const float* pn   = (const float*)d_in[5];
    const float* pow_ = (const float*)d_in[6];
    const float* pon  = (const float*)d_in[7];
    const float* pfw  = (const float*)d_in[8];
    const float* pfn  = (const float*)d_in[9];
    const float* cw   = (const float*)d_in[10];
    const float* cn   = (const float*)d_in[11];
    float* ws  = (float*)d_ws;
    float* out = (float*)d_out;

    hipLaunchKernelGGL(kB, dim3(82),   dim3(256), 0, stream,
                       syms, siv, pw, pn, pow_, pon, pfw, pfn, cw, cn, ws);
    hipLaunchKernelGGL(kA, dim3(512),  dim3(256), 0, stream, x, ws);
    hipLaunchKernelGGL(kC, dim3(256),  dim3(256), 0, stream, ws, shp);
    hipLaunchKernelGGL(kD, dim3(2048), dim3(256), 0, stream, ws, syms, siv, out);
}

// Round 6
// 384.626 us; speedup vs baseline: 1.4734x; 1.0530x over previous
//
#include <hip/hip_runtime.h>
#include <math.h>

// Cyborg stack machine: B=256, S=128, V=512, H=30, N_STACKS=2, R=2, DEPTH=4
// All stack/peek/output vectors live in span{ones, init_vec, syms0..29} (32-dim).
// kA (R11): split-f16 MFMA GEMM + T14 issue-early/write-late staging (x-load
//   latency no longer serializes each K-step through the DS-order chain).
// kC (R11): 1 barrier/step. pk broadcast via in-wave v_readlane (state is
//   replicated in every wave -> pkL LDS buffer + B2 barrier deleted; dot/Gram
//   FMAs take SGPR operands on each SIMD's private VALU instead of the shared
//   LDS pipe). DPP sum16 + 1 ds_swizzle xor16 for the norm reduce (R10-proven).

#define SS 128
#define VV 512
#define NROWS 208      // 8 pop + 8 pushop + 128 pushfn + 64 calc
#define ZOFF 1e-6f

// ws layout (float offsets)
#define OFF_I0   0                          // interp0: 32768*208
#define OFF_OC   (32768*208)                // out coords: 32768*32
#define OFF_GI   (OFF_OC + 32768*32)        // G[2][32][208]  (stack, basis, row)
#define OFF_M    (OFF_GI + 2*32*208)        // Gram 32*32
#define OFF_A    (OFF_M + 1024)             // A coef 208*3
#define OFF_Bc   (OFF_A + 624)              // B coef 208*3
#define OFF_W0   (OFF_Bc + 624)             // Wh/Wl f16: 2 x [208][512] halves

typedef _Float16 half8 __attribute__((ext_vector_type(8)));
typedef float f32x4 __attribute__((ext_vector_type(4)));

__device__ __forceinline__ float rlane(float v, int lane) {
    return __int_as_float(__builtin_amdgcn_readlane(__float_as_int(v), lane));
}
template <int CTRL>
__device__ __forceinline__ float dpp_add(float x) {
    int y = __builtin_amdgcn_update_dpp(0, __float_as_int(x), CTRL, 0xF, 0xF, true);
    return x + __int_as_float(y);
}
// full 16-lane row sum, result in all lanes of the row (pure VALU)
__device__ __forceinline__ float sum16(float x) {
    x = dpp_add<0xB1>(x);    // quad_perm [1,0,3,2]  (xor 1)
    x = dpp_add<0x4E>(x);    // quad_perm [2,3,0,1]  (xor 2)
    x = dpp_add<0x124>(x);   // row_ror:4
    x = dpp_add<0x128>(x);   // row_ror:8
    return x;
}
__device__ __forceinline__ float swz16(float x) {   // lane ^ 16 within 32-group
    return __int_as_float(__builtin_amdgcn_ds_swizzle(__float_as_int(x), 0x401F));
}

__device__ __forceinline__ const float* w_row(int r, const float* pw, const float* pow_,
                                              const float* pfw, const float* cw) {
    if (r < 8)   return pw   + r * 1536;
    if (r < 16)  return pow_ + (r - 8) * 1536;
    if (r < 144) return pfw  + (r - 16) * 1536;
    return cw + (r - 144) * 1536;
}
__device__ __forceinline__ const float* nw_row(int r, const float* pn, const float* pon,
                                               const float* pfn, const float* cn) {
    if (r < 8)   return pn   + r * 3;
    if (r < 16)  return pon  + (r - 8) * 3;
    if (r < 144) return pfn  + (r - 16) * 3;
    return cn + (r - 144) * 3;
}

// ---------------- kernel B: precompute tables ----------------
__global__ void kB(const float* __restrict__ syms, const float* __restrict__ siv,
                   const float* __restrict__ pw, const float* __restrict__ pn,
                   const float* __restrict__ pow_, const float* __restrict__ pon,
                   const float* __restrict__ pfw, const float* __restrict__ pfn,
                   const float* __restrict__ cw, const float* __restrict__ cn,
                   float* __restrict__ ws) {
    int blk = blockIdx.x, tid = threadIdx.x;
    if (blk < 64) {
        // G[jj][e][c] = basis_e . w_row(c)[(jj+1)*512 ..)
        int jj = blk >> 5, e = blk & 31;
        __shared__ float bas[512];
        for (int i = tid; i < 512; i += 256)
            bas[i] = (e == 0) ? 1.0f : ((e == 1) ? siv[i] : syms[(e - 2) * 512 + i]);
        __syncthreads();
        if (tid < NROWS) {
            int c = tid;
            const float4* w4 = (const float4*)(w_row(c, pw, pow_, pfw, cw) + (jj + 1) * 512);
            const float4* b4 = (const float4*)bas;
            float s = 0.f;
            for (int q = 0; q < 128; ++q) {
                float4 a = b4[q], b = w4[q];
                s += a.x * b.x + a.y * b.y + a.z * b.z + a.w * b.w;
            }
            ws[OFF_GI + (jj * 32 + e) * 208 + c] = s;
        }
    } else if (blk == 64) {
        // Gram M[m][mm]
        __shared__ float basw[32 * 512];
        for (int i = tid; i < 32 * 512; i += 256) {
            int m = i >> 9, v = i & 511;
            basw[i] = (m == 0) ? 1.0f : ((m == 1) ? siv[v] : syms[(m - 2) * 512 + v]);
        }
        __syncthreads();
        for (int p = tid; p < 1024; p += 256) {
            int m = p >> 5, mm = p & 31;
            const float4* a4 = (const float4*)(basw + m * 512);
            const float4* b4 = (const float4*)(basw + mm * 512);
            float s = 0.f;
            for (int q = 0; q < 128; ++q) {
                float4 a = a4[q], b = b4[q];
                s += a.x * b.x + a.y * b.y + a.z * b.z + a.w * b.w;
            }
            ws[OFF_M + p] = s;
        }
    } else if (blk == 65) {
        // folded NAND coefs: A=(2*sig-1)/||w||, B=1-sig   for (r, j)
        for (int idx = tid; idx < 624; idx += 256) {
            int r = idx / 3, j = idx % 3;
            const float4* w4 = (const float4*)(w_row(r, pw, pow_, pfw, cw) + j * 512);
            float s = 0.f;
            for (int q = 0; q < 128; ++q) {
                float4 b = w4[q];
                s += b.x * b.x + b.y * b.y + b.z * b.z + b.w * b.w;
            }
            float nrm = fmaxf(sqrtf(s), 1e-8f);
            float nwv = nw_row(r, pn, pon, pfn, cn)[j];
            float sig = 1.f / (1.f + expf(-nwv));
            ws[OFF_A + idx]  = (2.f * sig - 1.f) / nrm;
            ws[OFF_Bc + idx] = 1.f - sig;
        }
    } else {
        // gather w j=0 slice as split-f16 hi/lo: Wh/Wl [208][512] halves — 16 blocks
        int part = blk - 66;
        _Float16* whp = (_Float16*)(ws + OFF_W0);
        _Float16* wlp = whp + 208 * 512;
        for (int i = tid; i < 6656; i += 256) {
            int flat = part * 6656 + i;
            int c = flat >> 9, v = flat & 511;
            float wv = w_row(c, pw, pow_, pfw, cw)[v];
            _Float16 h = (_Float16)wv;
            whp[flat] = h;
            wlp[flat] = (_Float16)(wv - (float)h);
        }
    }
}

// ---------------- kernel A: interp0 via split-f16 MFMA GEMM ----------------
__global__ __launch_bounds__(256) void kA(const float* __restrict__ x, float* __restrict__ ws) {
    __shared__ half8 AH[2][256];   // [buf][mfrag*64 + fraglane]
    __shared__ half8 AL[2][256];
    __shared__ float red[256];
    __shared__ float invx[64];
    const int tid = threadIdx.x;
    const int wid = tid >> 6, l = tid & 63;
    const size_t bt0 = (size_t)blockIdx.x * 64;

    const int sr = tid >> 2, ss = tid & 3;
    const float* xp = x + (bt0 + sr) * 512 + ss * 8;
    const int wpos = (sr >> 4) * 64 + (sr & 15) + (ss << 4);   // frag slot

    const _Float16* whp = (const _Float16*)(ws + OFF_W0);
    const _Float16* wlp = whp + 208 * 512;

    const int t0 = (wid == 0) ? 0 : (1 + 3 * wid);   // 0,4,7,10
    const int nt = (wid == 0) ? 4 : 3;

    f32x4 acc[4][4];
#pragma unroll
    for (int m = 0; m < 4; ++m)
#pragma unroll
        for (int tt = 0; tt < 4; ++tt)
            acc[m][tt] = (f32x4){0.f, 0.f, 0.f, 0.f};

    float sumsq = 0.f;

    // prologue stage of kt=0
    {
        float v[8];
        *(float4*)v       = *(const float4*)(xp);
        *(float4*)(v + 4) = *(const float4*)(xp + 4);
        half8 hh, hl;
#pragma unroll
        for (int j = 0; j < 8; ++j) {
            sumsq += v[j] * v[j];
            _Float16 h = (_Float16)v[j];
            hh[j] = h;
            hl[j] = (_Float16)(v[j] - (float)h);
        }
        AH[0][wpos] = hh;
        AL[0][wpos] = hl;
    }
    __syncthreads();

    for (int kt = 0; kt < 16; ++kt) {
        const int buf = kt & 1;
        // 1) A-fragment LDS reads first (no DS-order dependence on staging writes)
        half8 ahm[4], alm[4];
#pragma unroll
        for (int m = 0; m < 4; ++m) {
            ahm[m] = AH[buf][m * 64 + l];
            alm[m] = AL[buf][m * 64 + l];
        }
        // 2) issue next-kt x loads EARLY (latency hides under MFMAs) [T14]
        float4 xv0, xv1;
        if (kt < 15) {
            xv0 = *(const float4*)(xp + (kt + 1) * 32);
            xv1 = *(const float4*)(xp + (kt + 1) * 32 + 4);
        }
        // 3) B loads + MFMAs
        const int kof = kt * 32 + (l >> 4) * 8;
#pragma unroll
        for (int tt = 0; tt < 4; ++tt) {
            if (tt < nt) {
                const int c = (t0 + tt) * 16 + (l & 15);
                half8 bh = *(const half8*)(whp + c * 512 + kof);
                half8 bl = *(const half8*)(wlp + c * 512 + kof);
#pragma unroll
                for (int m = 0; m < 4; ++m) {
                    acc[m][tt] = __builtin_amdgcn_mfma_f32_16x16x32_f16(ahm[m], bh, acc[m][tt], 0, 0, 0);
                    acc[m][tt] = __builtin_amdgcn_mfma_f32_16x16x32_f16(ahm[m], bl, acc[m][tt], 0, 0, 0);
                    acc[m][tt] = __builtin_amdgcn_mfma_f32_16x16x32_f16(alm[m], bh, acc[m][tt], 0, 0, 0);
                }
            }
        }
        // 4) write-late: convert + LDS store of next tile after MFMAs issued
        if (kt < 15) {
            float v[8];
            *(float4*)v = xv0; *(float4*)(v + 4) = xv1;
            half8 hh, hl;
#pragma unroll
            for (int j = 0; j < 8; ++j) {
                sumsq += v[j] * v[j];
                _Float16 h = (_Float16)v[j];
                hh[j] = h;
                hl[j] = (_Float16)(v[j] - (float)h);
            }
            AH[buf ^ 1][wpos] = hh;
            AL[buf ^ 1][wpos] = hl;
        }
        __syncthreads();
    }

    red[tid] = sumsq;
    __syncthreads();
    if (tid < 64) {
        float s = red[tid * 4] + red[tid * 4 + 1] + red[tid * 4 + 2] + red[tid * 4 + 3];
        invx[tid] = 1.f / fmaxf(sqrtf(s), 1e-8f);
    }
    __syncthreads();

    // epilogue: interp0 = A0*|dot|*invx + B0.  D frag: col=lane&15, row=(lane>>4)*4+reg
#pragma unroll
    for (int tt = 0; tt < 4; ++tt) {
        if (tt < nt) {
            const int c = (t0 + tt) * 16 + (l & 15);
            const float A0 = ws[OFF_A + c * 3];
            const float B0 = ws[OFF_Bc + c * 3];
#pragma unroll
            for (int m = 0; m < 4; ++m) {
                const int rbase = m * 16 + (l >> 4) * 4;
#pragma unroll
                for (int j = 0; j < 4; ++j) {
                    const float ix = invx[rbase + j];
                    ws[OFF_I0 + (bt0 + rbase + j) * 208 + c] = A0 * fabsf(acc[m][tt][j]) * ix + B0;
                }
            }
        }
    }
}

// ---------------- kernel C: serial scan, 1 barrier/step, readlane broadcast ----------------
// Every thread owns row r = (wid==3)? 144+l : tid  (tid 144..191 = valid junk).
// All waves: replicated stack state + Mrow[32]. pk[mm] gathered from the wave's
// OWN lanes via v_readlane (state replicated) -> no pkL buffer, no B2 barrier.
// Per step: gates(nndL[t&1]) -> update -> pkp -> readlane dots+gram (SGPR ops)
//   -> DPP sum16 + swz16 -> iq -> nnd -> nndL[(t+1)&1] / oc -> ONE barrier.
__global__ __attribute__((amdgpu_flat_work_group_size(256, 256), amdgpu_waves_per_eu(1, 1)))
void kC(float* __restrict__ ws, const float* __restrict__ sharp) {
    __shared__ float nndL[2][144];
    const int b = blockIdx.x, tid = threadIdx.x;
    const int wid = tid >> 6, l = tid & 63;
    const int k = l >> 5, m = l & 31;
    const int isW3 = (wid == 3);
    const int isRow = (tid < 144);
    const int r = isW3 ? (144 + l) : tid;          // owned NAND row

    const float* GI = ws + OFF_GI;
    float G[64];
#pragma unroll
    for (int i = 0; i < 32; ++i) {
        G[i]      = GI[i * 208 + r];
        G[32 + i] = GI[(32 + i) * 208 + r];
    }
    const float A1 = ws[OFF_A + r * 3 + 1],  A2 = ws[OFF_A + r * 3 + 2];
    const float B1 = ws[OFF_Bc + r * 3 + 1], B2 = ws[OFF_Bc + r * 3 + 2];
    float Mrow[32];
#pragma unroll
    for (int q = 0; q < 8; ++q) {
        float4 mr = *(const float4*)(ws + OFF_M + m * 32 + 4 * q);
        Mrow[4*q] = mr.x; Mrow[4*q+1] = mr.y; Mrow[4*q+2] = mr.z; Mrow[4*q+3] = mr.w;
    }
    const float sh = sharp[k];

    // replicated stack state
    float st[4], p[4];
#pragma unroll
    for (int d = 0; d < 4; ++d) {
        st[d] = (d == 1) ? ((m == 1) ? 1.f : 0.f) : ((m == 0) ? ZOFF : 0.f);
        p[d] = (d == 1) ? 1.f : 0.f;
    }
    float pk = st[0] * p[0] + st[1] * p[1] + st[2] * p[2] + st[3] * p[3];
    float pkOther = __shfl_xor(pk, 32);

    const float* i0base = ws + OFF_I0 + (size_t)b * SS * 208;
    const int ioff = isW3 ? 0 : 1;                 // rows consume i0(t+1), w3 i0(t)
    float i0pro = i0base[r];                       // i0(0) for prologue
    float i0use = i0base[(size_t)ioff * 208 + r];  // rows: i0(1), w3: i0(0)

    // CA: in-wave readlane gather of pkp; dots (G) + gram (Mrow) with SGPR ops
    auto CA = [&](float pp, float po, float iv) -> float {
        float gq0a = 0.f, gq0b = 0.f, gq1a = 0.f, gq1b = 0.f;
        float d1a = 0.f, d1b = 0.f, d2a = 0.f, d2b = 0.f;
#pragma unroll
        for (int mm = 0; mm < 32; ++mm) {
            float v0 = rlane(pp, mm);        // pk0[mm]
            float v1 = rlane(pp, 32 + mm);   // pk1[mm]
            if (mm & 1) {
                gq0b += Mrow[mm] * v0;  gq1b += Mrow[mm] * v1;
                d1b  += G[mm] * v0;     d2b  += G[32 + mm] * v1;
            } else {
                gq0a += Mrow[mm] * v0;  gq1a += Mrow[mm] * v1;
                d1a  += G[mm] * v0;     d2a  += G[32 + mm] * v1;
            }
        }
        // both quadratic forms per lane: own pk0/pk1 component times (M.pk)
        float pm0 = (k ? po : pp) * (gq0a + gq0b);
        float pm1 = (k ? pp : po) * (gq1a + gq1b);
        float q0 = sum16(pm0); q0 += swz16(q0);
        float q1 = sum16(pm1); q1 += swz16(q1);
        float iq0 = __frsqrt_rn(fmaxf(q0, 1e-16f));
        float iq1 = __frsqrt_rn(fmaxf(q1, 1e-16f));
        float dd1 = d1a + d1b, dd2 = d2a + d2b;
        return iv * (A1 * fabsf(dd1) * iq0 + B1) * (A2 * fabsf(dd2) * iq1 + B2);
    };

    // ---- prologue: nnd(0) -> nndL[0] ----
    {
        float nv0 = CA(pk, pkOther, i0pro);
        if (isRow) nndL[0][tid] = nv0;
    }
    __syncthreads();

    for (int t = 0; t < SS; ++t) {
        // early prefetch of next i0 (global latency hides under this step)
        int nidx = t + 1 + ioff; if (nidx > SS - 1) nidx = SS - 1;
        float i0nxt = i0base[(size_t)nidx * 208 + r];

        const float* nb = nndL[t & 1];
        // ---- gates + push_val + state update (replicated in all waves) ----
        float4 gp4 = *(const float4*)(nb + 4 * k);
        float4 gq4 = *(const float4*)(nb + 8 + 4 * k);
        float prp0 = 1.f / (1.f + __expf((fmaxf(gp4.z, gp4.w) - fmaxf(gp4.x, gp4.y)) * sh));
        float prq0 = 1.f / (1.f + __expf((fmaxf(gq4.z, gq4.w) - fmaxf(gq4.x, gq4.y)) * sh));
        float prp1 = 1.f - prp0, prq1 = 1.f - prq0;
        float prx = 0.f, pry = 0.f;
        if (m >= 2) {
            float2 pr2 = *(const float2*)(nb + 16 + 64 * k + 2 * m - 4);
            prx = pr2.x; pry = pr2.y;
        }
        float4 t30 = *(const float4*)(nb + 16 + 64 * k + 60);
        float pk0m = k ? pkOther : pk;
        float pk1m = k ? pk : pkOther;
        float pvc = prx + pry + (t30.x + t30.y) * pk0m + (t30.z + t30.w) * pk1m;

        float zc = (m == 0) ? ZOFF : 0.f;
        float s1[4], p1[4];
#pragma unroll
        for (int d = 0; d < 4; ++d) {
            float ps = st[d] * (1.f - p[d]) + zc * p[d];
            s1[d] = ps * prp0 + st[d] * prp1;
            p1[d] = p[(d + 1) & 3] * prp0 + p[d] * prp1;
        }
#pragma unroll
        for (int d = 0; d < 4; ++d) {
            float pu = p1[(d + 3) & 3];
            float su = s1[d] * (1.f - pu) + pvc * pu;
            st[d] = su * prq0 + s1[d] * prq1;
            p[d] = pu * prq0 + p1[d] * prq1;
        }
        float pkp = st[0] * p[0] + st[1] * p[1] + st[2] * p[2] + st[3] * p[3];
        float pkpOth = __shfl_xor(pkp, 32);

        // ---- fused gram + dots + nnd (no barrier needed before this!) ----
        float nv = CA(pkp, pkpOth, i0use);
        if (isRow) nndL[(t + 1) & 1][tid] = nv;
        if (isW3) {
            // out coords via lane ops over per-lane nnd2 (calc row 144+lane)
            float s60 = rlane(nv, 60), s61 = rlane(nv, 61);
            float s62 = rlane(nv, 62), s63 = rlane(nv, 63);
            int src = (m >= 2) ? (2 * m - 4) : 0;
            float cx = __shfl(nv, src);
            float cy = __shfl(nv, src + 1);
            if (m < 2) { cx = 0.f; cy = 0.f; }
            if (l < 32) {
                float oc = cx + cy + (s60 + s61) * pkp + (s62 + s63) * pkpOth;
                ws[OFF_OC + ((size_t)b * SS + t) * 32 + m] = oc;
            }
        }
        __syncthreads();   // nndL(t+1) visible for next step
        pk = pkp;
        pkOther = pkpOth;
        i0use = i0nxt;
    }
}

// ---------------- kernel D: expand coords -> 512-dim output (barrier-free) ----------------
__global__ __launch_bounds__(256) void kD(const float* __restrict__ ws, const float* __restrict__ syms,
                                          const float* __restrict__ siv, float* __restrict__ out) {
    int t = threadIdx.x;
    int rg = t >> 6;
    int vc = (t & 63) * 8;
    size_t r0 = (size_t)blockIdx.x * 16 + rg * 4;
    const float* oc = ws + OFF_OC;
    float acc[4][8];
    float4 sv0 = *(const float4*)(siv + vc);
    float4 sv1 = *(const float4*)(siv + vc + 4);
#pragma unroll
    for (int rr = 0; rr < 4; ++rr) {
        float c0 = oc[(r0 + rr) * 32 + 0];
        float c1 = oc[(r0 + rr) * 32 + 1];
        acc[rr][0] = c0 + c1 * sv0.x; acc[rr][1] = c0 + c1 * sv0.y;
        acc[rr][2] = c0 + c1 * sv0.z; acc[rr][3] = c0 + c1 * sv0.w;
        acc[rr][4] = c0 + c1 * sv1.x; acc[rr][5] = c0 + c1 * sv1.y;
        acc[rr][6] = c0 + c1 * sv1.z; acc[rr][7] = c0 + c1 * sv1.w;
    }
    for (int mm = 0; mm < 30; ++mm) {
        float4 b0 = *(const float4*)(syms + mm * 512 + vc);
        float4 b1 = *(const float4*)(syms + mm * 512 + vc + 4);
#pragma unroll
        for (int rr = 0; rr < 4; ++rr) {
            float c = oc[(r0 + rr) * 32 + 2 + mm];
            acc[rr][0] += c * b0.x; acc[rr][1] += c * b0.y;
            acc[rr][2] += c * b0.z; acc[rr][3] += c * b0.w;
            acc[rr][4] += c * b1.x; acc[rr][5] += c * b1.y;
            acc[rr][6] += c * b1.z; acc[rr][7] += c * b1.w;
        }
    }
#pragma unroll
    for (int rr = 0; rr < 4; ++rr) {
        float* o = out + (r0 + rr) * 512 + vc;
        *(float4*)o       = make_float4(acc[rr][0], acc[rr][1], acc[rr][2], acc[rr][3]);
        *(float4*)(o + 4) = make_float4(acc[rr][4], acc[rr][5], acc[rr][6], acc[rr][7]);
    }
}

extern "C" void kernel_launch(void* const* d_in, const int* in_sizes, int n_in,
                              void* d_out, int out_size, void* d_ws, size_t ws_size,
                              hipStream_t stream) {
    const float* x    = (const float*)d_in[0];
    const float* syms = (const float*)d_in[1];
    const float* siv  = (const float*)d_in[2];
    const float* shp  = (const float*)d_in[3];
    const float* pw   = (const float*)d_in[4];
    const float* pn   = (const float*)d_in[5];
    const float* pow_ = (const float*)d_in[6];
    const float* pon  = (const float*)d_in[7];
    const float* pfw  = (const float*)d_in[8];
    const float* pfn  = (const float*)d_in[9];
    const float* cw   = (const float*)d_in[10];
    const float* cn   = (const float*)d_in[11];
    float* ws  = (float*)d_ws;
    float* out = (float*)d_out;

    hipLaunchKernelGGL(kB, dim3(82),   dim3(256), 0, stream,
                       syms, siv, pw, pn, pow_, pon, pfw, pfn, cw, cn, ws);
    hipLaunchKernelGGL(kA, dim3(512),  dim3(256), 0, stream, x, ws);
    hipLaunchKernelGGL(kC, dim3(256),  dim3(256), 0, stream, ws, shp);
    hipLaunchKernelGGL(kD, dim3(2048), dim3(256), 0, stream, ws, syms, siv, out);
}